// Round 3
// baseline (541.742 us; speedup 1.0000x reference)
//
#include <hip/hip_runtime.h>

// LoG = GaussianBlur(3x3,sigma=1,REFLECT_101) -> Laplacian(9x9,REFLECT_101) -> +1 -> clip[0,255]
// x: [32,512,512,3] f32 NHWC.
//
// Interior factorization (exact where no reflect triggers, i.e. rows/cols 5..506):
//   Sg = S9 conv g3 (11-tap), Dg = D9 conv g3 (11-tap)
//   hS[row] = horz(Sg, x[row]), hD[row] = horz(Dg, x[row])
//   out[r]  = sum_k Sg[k]*hD[r-5+k] + Dg[k]*hS[r-5+k] + 1
// Border cols (pc<5 / pc>506) and border rows use exact two-stage folded weights
// w[pc][m] = sum_j F9[j] * sum_i g[i] * [R1(R2(pc-4+j)-1+i)==m], m in 0..9.
//
// Structure: full-row scanline blocks (384 thr x 1 float4), vertical conv in a
// 12-slot register ring, x staged via async global_load_lds (3-row chunks,
// double-buffered). Border rows 0..4/507..511 done by 2 small blocks per image.

#define NT    384
#define HIMG  512
#define ROWF  1536          // floats per image row (512*3)
#define CH    3             // rows per staged chunk
#define BUFF  (CH*ROWF)     // 4608 floats per buffer

__device__ __forceinline__ int reflect101(int i, int n) {
    i = (i < 0) ? -i : i;
    return (i >= n) ? (2*n - 2 - i) : i;
}

// 11-tap composite kernels (double-precision folded, A=exp(-.5)/(1+2exp(-.5)))
__device__ constexpr float SGc[11] = {
    0.27406861900052384f, 2.6444117140031430f, 11.562892047006810f,
    30.192548952004191f, 52.163039333992666f, 62.326078667985332f,
    52.163039333992666f, 30.192548952004191f, 11.562892047006810f,
    2.6444117140031430f, 0.27406861900052384f};
__device__ constexpr float DGc[11] = {
    0.27406861900052384f, 1.5481372380010477f, 3.1777941429984285f,
    1.8074510479958093f, -3.4518627619989523f, -6.7111765719937139f,
    -3.4518627619989523f, 1.8074510479958093f, 3.1777941429984285f,
    1.5481372380010477f, 0.27406861900052384f};

__device__ __forceinline__ void gload1k(const float* g, float* l) {
    __builtin_amdgcn_global_load_lds(
        (const __attribute__((address_space(1))) void*)g,
        (__attribute__((address_space(3))) void*)l, 16, 0, 0);
}

// stage 3 contiguous rows (18 KB): wave w -> segments 3w..3w+2 (1 KB each)
__device__ __forceinline__ void prefetch3(const float* g, float* l, int tid) {
    const int wave = tid >> 6, lane = tid & 63;
    const float* gp = g + wave*768 + lane*4;
    float* lp = l + wave*768;
    #pragma unroll
    for (int i = 0; i < 3; ++i) gload1k(gp + i*256, lp + i*256);
}

// stage 5 contiguous rows (30 KB): wave w -> segments 5w..5w+4
__device__ __forceinline__ void prefetch5(const float* g, float* l, int tid) {
    const int wave = tid >> 6, lane = tid & 63;
    const float* gp = g + wave*1280 + lane*4;
    float* lp = l + wave*1280;
    #pragma unroll
    for (int i = 0; i < 5; ++i) gload1k(gp + i*256, lp + i*256);
}

// horizontal 11-taps for one float4 column group; exact border handling
__device__ __forceinline__ void compute_h(const float* __restrict__ row, int cq,
        const float* __restrict__ wSt, const float* __restrict__ wDt,
        float4& hs, float4& hd) {
    if (cq >= 4 && cq <= 379) {
        // interior: aligned 36-float window [4cq-16, 4cq+20), 9x ds_read_b128
        float w[36];
        const float4* wp = (const float4*)(row + 4*cq - 16);
        #pragma unroll
        for (int q = 0; q < 9; ++q) {
            float4 v = wp[q];
            w[4*q+0] = v.x; w[4*q+1] = v.y; w[4*q+2] = v.z; w[4*q+3] = v.w;
        }
        float hsv[4], hdv[4];
        #pragma unroll
        for (int j = 0; j < 4; ++j) {
            float c = w[j+16];
            float s = SGc[5]*c, d = DGc[5]*c;
            #pragma unroll
            for (int k = 0; k < 5; ++k) {  // symmetric pairs
                float p = w[j+1+3*k] + w[j+31-3*k];
                s = fmaf(SGc[k], p, s);
                d = fmaf(DGc[k], p, d);
            }
            hsv[j] = s; hdv[j] = d;
        }
        hs = make_float4(hsv[0],hsv[1],hsv[2],hsv[3]);
        hd = make_float4(hdv[0],hdv[1],hdv[2],hdv[3]);
    } else {
        float hsv[4], hdv[4];
        #pragma unroll
        for (int j = 0; j < 4; ++j) {
            const int fc = 4*cq + j;
            const int pc = fc / 3;
            const int ch = fc - 3*pc;
            float s = 0.f, d = 0.f;
            if (pc <= 4) {
                #pragma unroll
                for (int m = 0; m < 10; ++m) {
                    float xv = row[3*m + ch];
                    s = fmaf(wSt[pc*10+m], xv, s);
                    d = fmaf(wDt[pc*10+m], xv, d);
                }
            } else if (pc >= 507) {
                const int p = 511 - pc;
                #pragma unroll
                for (int m = 0; m < 10; ++m) {
                    float xv = row[3*(511-m) + ch];
                    s = fmaf(wSt[p*10+m], xv, s);
                    d = fmaf(wDt[p*10+m], xv, d);
                }
            } else {  // pc == 5 or 506: standard, in-bounds
                #pragma unroll
                for (int k = 0; k < 11; ++k) {
                    float xv = row[fc - 15 + 3*k];
                    s = fmaf(SGc[k], xv, s);
                    d = fmaf(DGc[k], xv, d);
                }
            }
            hsv[j] = s; hdv[j] = d;
        }
        hs = make_float4(hsv[0],hsv[1],hsv[2],hsv[3]);
        hd = make_float4(hdv[0],hdv[1],hdv[2],hdv[3]);
    }
}

// one scan step at ring phase S = g mod 12
template<int S>
__device__ __forceinline__ void do_step(const float* __restrict__ row, int cq,
        const float* __restrict__ wSt, const float* __restrict__ wDt,
        float4 (&acc)[12], bool fin, float* __restrict__ outq, int r_abs) {
    float4 hs, hd;
    compute_h(row, cq, wSt, wDt, hs, hd);
    #pragma unroll
    for (int k = 0; k <= 10; ++k) {
        const int sl = (S - k + 24) % 12;        // slot of row g-k
        float4 a = acc[sl];
        a.x = fmaf(SGc[k], hd.x, a.x); a.y = fmaf(SGc[k], hd.y, a.y);
        a.z = fmaf(SGc[k], hd.z, a.z); a.w = fmaf(SGc[k], hd.w, a.w);
        a.x = fmaf(DGc[k], hs.x, a.x); a.y = fmaf(DGc[k], hs.y, a.y);
        a.z = fmaf(DGc[k], hs.z, a.z); a.w = fmaf(DGc[k], hs.w, a.w);
        acc[sl] = a;
    }
    if (fin) {                                    // row g-10 complete
        const int fs = (S + 2) % 12;
        float4 o = acc[fs];
        o.x = fminf(fmaxf(o.x, 0.f), 255.f);
        o.y = fminf(fmaxf(o.y, 0.f), 255.f);
        o.z = fminf(fmaxf(o.z, 0.f), 255.f);
        o.w = fminf(fmaxf(o.w, 0.f), 255.f);
        *(float4*)(outq + (size_t)r_abs * ROWF) = o;
        acc[fs] = make_float4(1.f,1.f,1.f,1.f);
    }
    acc[(S+1)%12] = make_float4(1.f,1.f,1.f,1.f);  // clear slot for row g+1
}

__global__ __launch_bounds__(NT, 3)
void log_scan(const float* __restrict__ x, float* __restrict__ out) {
    __shared__ __align__(16) float smem[2*BUFF + 200];   // 37.6 KB
    float* buf0 = smem;
    float* buf1 = smem + BUFF;
    float* wSt  = smem + 2*BUFF;
    float* wDt  = smem + 2*BUFF + 100;

    const int tid = threadIdx.x;
    const int img = blockIdx.y;
    const float* xn = x   + (size_t)img * HIMG * ROWF;
    float* on       = out + (size_t)img * HIMG * ROWF;
    float* outq     = on + 4*tid;

    // folded two-stage border weights: w[pc][m], pc 0..4, m 0..9
    if (tid < 100) {
        const int f = tid / 50, rem = tid % 50, pc = rem / 10, m = rem % 10;
        const double F9s[9] = {1,8,28,56,70,56,28,8,1};
        const double F9d[9] = {1,4,4,-4,-10,-4,4,4,1};
        const double A = 0.27406861900052384, B = 0.45186276199895232;
        const double g3[3] = {A, B, A};
        double acc = 0.0;
        for (int j = 0; j < 9; ++j) {
            int b = reflect101(pc - 4 + j, HIMG);
            double fj = f ? F9d[j] : F9s[j];
            for (int i = 0; i < 3; ++i)
                if (reflect101(b - 1 + i, HIMG) == m) acc += fj * g3[i];
        }
        (f ? wDt : wSt)[pc*10 + m] = (float)acc;
    }

    if (blockIdx.x >= 2) {
        // ---- band block: outputs rows r0..r0+31 (all in 5..506), scans 42 x-rows ----
        const int band = blockIdx.x - 2;
        const int r0 = (band == 15) ? 475 : (5 + 32*band);  // band 15 overlaps 14 (benign)
        const int g0 = r0 - 5;
        prefetch3(xn + (size_t)g0*ROWF, buf0, tid);          // chunk 0
        float4 acc[12];
        #pragma unroll
        for (int i = 0; i < 12; ++i) acc[i] = make_float4(1.f,1.f,1.f,1.f);

        for (int cc = 0; cc < 3; ++cc) {                     // 12 steps = 4 chunks each
            const int c0 = 4*cc;
            const int gb = 12*cc;
            const bool fA = (cc > 0);
            __syncthreads();
            prefetch3(xn + (size_t)(g0 + CH*(c0+1))*ROWF, buf1, tid);
            do_step<0>(buf0 + 0*ROWF, tid, wSt, wDt, acc, fA, outq, r0+gb-10);
            do_step<1>(buf0 + 1*ROWF, tid, wSt, wDt, acc, fA, outq, r0+gb-9);
            do_step<2>(buf0 + 2*ROWF, tid, wSt, wDt, acc, fA, outq, r0+gb-8);
            __syncthreads();
            prefetch3(xn + (size_t)(g0 + CH*(c0+2))*ROWF, buf0, tid);
            do_step<3>(buf1 + 0*ROWF, tid, wSt, wDt, acc, fA, outq, r0+gb-7);
            do_step<4>(buf1 + 1*ROWF, tid, wSt, wDt, acc, fA, outq, r0+gb-6);
            do_step<5>(buf1 + 2*ROWF, tid, wSt, wDt, acc, fA, outq, r0+gb-5);
            __syncthreads();
            prefetch3(xn + (size_t)(g0 + CH*(c0+3))*ROWF, buf1, tid);
            do_step<6>(buf0 + 0*ROWF, tid, wSt, wDt, acc, fA, outq, r0+gb-4);
            do_step<7>(buf0 + 1*ROWF, tid, wSt, wDt, acc, fA, outq, r0+gb-3);
            do_step<8>(buf0 + 2*ROWF, tid, wSt, wDt, acc, fA, outq, r0+gb-2);
            __syncthreads();
            prefetch3(xn + (size_t)(g0 + CH*(c0+4))*ROWF, buf0, tid);
            do_step<9>(buf1 + 0*ROWF, tid, wSt, wDt, acc, fA, outq, r0+gb-1);
            do_step<10>(buf1 + 1*ROWF, tid, wSt, wDt, acc, true, outq, r0+gb);
            do_step<11>(buf1 + 2*ROWF, tid, wSt, wDt, acc, true, outq, r0+gb+1);
        }
        // epilogue: chunks 12 (in buf0) & 13, steps g=36..41
        __syncthreads();
        prefetch3(xn + (size_t)(g0 + CH*13)*ROWF, buf1, tid);
        do_step<0>(buf0 + 0*ROWF, tid, wSt, wDt, acc, true, outq, r0+26);
        do_step<1>(buf0 + 1*ROWF, tid, wSt, wDt, acc, true, outq, r0+27);
        do_step<2>(buf0 + 2*ROWF, tid, wSt, wDt, acc, true, outq, r0+28);
        __syncthreads();
        do_step<3>(buf1 + 0*ROWF, tid, wSt, wDt, acc, true, outq, r0+29);
        do_step<4>(buf1 + 1*ROWF, tid, wSt, wDt, acc, true, outq, r0+30);
        do_step<5>(buf1 + 2*ROWF, tid, wSt, wDt, acc, true, outq, r0+31);
    } else {
        // ---- border block: top (bx=0) rows 0..4, bottom (bx=1) rows 507..511 ----
        const int top = (blockIdx.x == 0);
        const int base = top ? 0 : (HIMG - 10);      // x rows base..base+9
        prefetch5(xn + (size_t)base*ROWF, smem, tid); // rows base..base+4 -> lds rows 0..4
        float4 accB[5];
        #pragma unroll
        for (int r = 0; r < 5; ++r) accB[r] = make_float4(1.f,1.f,1.f,1.f);

        #pragma unroll
        for (int half = 0; half < 2; ++half) {
            __syncthreads();
            for (int q = 0; q < 5; ++q) {
                float4 hs, hd;
                compute_h(smem + q*ROWF, tid, wSt, wDt, hs, hd);
                const int qq = half*5 + q;           // lds-logical row 0..9
                const int m = top ? qq : (9 - qq);   // folded weight index
                #pragma unroll
                for (int r = 0; r < 5; ++r) {
                    float ws = wSt[r*10+m], wd = wDt[r*10+m];
                    float4 a = accB[r];
                    a.x = fmaf(ws, hd.x, a.x); a.y = fmaf(ws, hd.y, a.y);
                    a.z = fmaf(ws, hd.z, a.z); a.w = fmaf(ws, hd.w, a.w);
                    a.x = fmaf(wd, hs.x, a.x); a.y = fmaf(wd, hs.y, a.y);
                    a.z = fmaf(wd, hs.z, a.z); a.w = fmaf(wd, hs.w, a.w);
                    accB[r] = a;
                }
            }
            if (half == 0) {
                __syncthreads();                     // readers done before overwrite
                prefetch5(xn + (size_t)(base+5)*ROWF, smem, tid);
            }
        }
        #pragma unroll
        for (int r = 0; r < 5; ++r) {
            const int r_abs = top ? r : (511 - r);
            float4 o = accB[r];
            o.x = fminf(fmaxf(o.x, 0.f), 255.f);
            o.y = fminf(fmaxf(o.y, 0.f), 255.f);
            o.z = fminf(fmaxf(o.z, 0.f), 255.f);
            o.w = fminf(fmaxf(o.w, 0.f), 255.f);
            *(float4*)(on + (size_t)r_abs*ROWF + 4*tid) = o;
        }
    }
}

extern "C" void kernel_launch(void* const* d_in, const int* in_sizes, int n_in,
                              void* d_out, int out_size, void* d_ws, size_t ws_size,
                              hipStream_t stream) {
    const float* x = (const float*)d_in[0];
    float* outp = (float*)d_out;
    const int nimg = in_sizes[0] / (HIMG * ROWF);
    dim3 grid(18, nimg, 1);   // x: 0,1 = border blocks; 2..17 = 16 row-bands
    log_scan<<<grid, dim3(NT, 1, 1), 0, stream>>>(x, outp);
}